// Round 6
// baseline (152.470 us; speedup 1.0000x reference)
//
#include <hip/hip_runtime.h>

// Problem constants (from reference setup_inputs)
#define NROW 10000   // N*N
#define NN   100     // N
#define PP   12      // p
#define BB   128     // batch

typedef float f32x4 __attribute__((ext_vector_type(4)));

// ---------------------------------------------------------------------------
// Kernel 1: F[row] = sum_k g[row,k] * w[k]^2
// 625 blocks x 256 threads; one wave owns 4 rows (2500 waves x 4 = 10000).
// w^2 lives in VGPRs (40 x f32x4 per lane, squared at load) -> the hot loop
// is a PURE non-temporal g stream + FMA: no LDS, no barrier, no second
// memory stream (round-5's w2-via-L1 thrashed the 32KB L1 with a 40KB
// working set). Two rows in flight per wave for load-latency hiding.
// __launch_bounds__(256,2): cap VGPR at 256 -> 2 waves/SIMD resident.
// ---------------------------------------------------------------------------
__global__ __launch_bounds__(256, 2) void f_kernel(const float* __restrict__ g,
                                                   const float* __restrict__ w,
                                                   float* __restrict__ Fout) {
    const int lane    = threadIdx.x & 63;
    const int wave_id = blockIdx.x * 4 + (threadIdx.x >> 6);   // 0..2499
    const f32x4* wv4  = (const f32x4*)w;

    f32x4 wreg[40];                       // 160 VGPRs of w^2
    #pragma unroll
    for (int i = 0; i < 40; ++i) {
        const int c = i * 64 + lane;      // only i==39 is ragged (2500 = 39*64+4)
        f32x4 v = (c < NROW / 4) ? wv4[c] : (f32x4){0.f, 0.f, 0.f, 0.f};
        wreg[i] = v * v;
    }

    const int r0 = wave_id * 4;
    #pragma unroll
    for (int rp = 0; rp < 2; ++rp) {
        const int ra = r0 + rp * 2, rb = ra + 1;
        const f32x4* ga = (const f32x4*)(g + (size_t)ra * NROW);
        const f32x4* gb = (const f32x4*)(g + (size_t)rb * NROW);
        f32x4 acc_a = {0.f, 0.f, 0.f, 0.f}, acc_b = {0.f, 0.f, 0.f, 0.f};
        #pragma unroll
        for (int i = 0; i < 40; ++i) {
            const int c = i * 64 + lane;
            if (c < NROW / 4) {
                acc_a += __builtin_nontemporal_load(ga + c) * wreg[i];
                acc_b += __builtin_nontemporal_load(gb + c) * wreg[i];
            }
        }
        float sa = acc_a.x + acc_a.y + acc_a.z + acc_a.w;
        float sb = acc_b.x + acc_b.y + acc_b.z + acc_b.w;
        #pragma unroll
        for (int off = 32; off; off >>= 1) {
            sa += __shfl_down(sa, off, 64);
            sb += __shfl_down(sb, off, 64);
        }
        if (lane == 0) { Fout[ra] = sa; Fout[rb] = sb; }
    }
}

// ---------------------------------------------------------------------------
// Kernel 2: Z[b,n] = sum_p sum_m softmax_m(-alpha[x_i[b,p]] * F[n,m]) * x[b,m,p]
// 512 blocks = (b, quarter-of-rows): rows are independent, so use the full
// chip. 16 lanes per row n; lane q<12 computes the whole softmax for p=q
// (100 serial iters, vs 300 in round 5). Only the block's 25 F-rows staged
// (10 KB, stride 101 -> conflict-free). Group-of-16 shfl_xor reduces.
// Softmax stabilized via per-row min of F (alpha > 0 => max(-a*F) = -a*minF).
// ---------------------------------------------------------------------------
__global__ __launch_bounds__(512) void z_kernel(const float* __restrict__ x,
                                                const float* __restrict__ alphas,
                                                const int*   __restrict__ xi,
                                                const float* __restrict__ F,
                                                float* __restrict__ Z) {
    const int bid = blockIdx.x;          // b*4 + nq
    const int b   = bid >> 2;
    const int nq  = bid & 3;
    const int n0  = nq * 25;
    __shared__ float Fs[25 * 101];
    __shared__ float xs[NN * PP];
    __shared__ float al[PP];
    const int tid = threadIdx.x;

    for (int j = tid; j < 25 * NN; j += 512) {
        int r = j / NN, m = j - r * NN;
        Fs[r * 101 + m] = F[(n0 + r) * NN + m];
    }
    for (int j = tid; j < NN * PP; j += 512)
        xs[j] = x[(size_t)b * (NN * PP) + j];
    if (tid < PP) al[tid] = alphas[xi[b * PP + tid]];
    __syncthreads();

    const int nl = tid >> 4;             // 0..31 (25 active)
    const int q  = tid & 15;
    if (nl < 25) {
        const float* Fr = &Fs[nl * 101];

        float rmin = 3.4e38f;
        for (int m = q; m < NN; m += 16) rmin = fminf(rmin, Fr[m]);
        rmin = fminf(rmin, __shfl_xor(rmin, 1, 64));
        rmin = fminf(rmin, __shfl_xor(rmin, 2, 64));
        rmin = fminf(rmin, __shfl_xor(rmin, 4, 64));
        rmin = fminf(rmin, __shfl_xor(rmin, 8, 64));

        float zacc = 0.f;
        if (q < PP) {
            const float a = al[q];
            float num = 0.f, den = 0.f;
            for (int m = 0; m < NN; m++) {
                float e = __expf(a * (rmin - Fr[m]));   // exponent <= 0
                num += e * xs[m * PP + q];
                den += e;
            }
            zacc = num / den;                           // den >= 1
        }
        zacc += __shfl_xor(zacc, 1, 64);
        zacc += __shfl_xor(zacc, 2, 64);
        zacc += __shfl_xor(zacc, 4, 64);
        zacc += __shfl_xor(zacc, 8, 64);
        if (q == 0) Z[b * NN + n0 + nl] = zacc;
    }
}

extern "C" void kernel_launch(void* const* d_in, const int* in_sizes, int n_in,
                              void* d_out, int out_size, void* d_ws, size_t ws_size,
                              hipStream_t stream) {
    const float* x      = (const float*)d_in[0];   // [128,100,12]
    const float* g      = (const float*)d_in[1];   // [10000,10000]
    const float* w      = (const float*)d_in[2];   // [10000,1]
    const float* alphas = (const float*)d_in[3];   // [4000,1]
    const int*   xi     = (const int*)d_in[4];     // [128,12]

    float* Z = (float*)d_out;            // [128,100] -> 12800 floats
    float* F = (float*)d_out + BB * NN;  // [10000]   -> next 10000 floats

    f_kernel<<<625, 256, 0, stream>>>(g, w, F);
    z_kernel<<<BB * 4, 512, 0, stream>>>(x, alphas, xi, F, Z);
}

// Round 7
// 82.263 us; speedup vs baseline: 1.8534x; 1.8534x over previous
//
#include <hip/hip_runtime.h>

// Problem constants (from reference setup_inputs)
#define NROW 10000   // N*N
#define NN   100     // N
#define PP   12      // p
#define BB   128     // batch
#define RPB  8       // rows per block in f_kernel

typedef float f32x4 __attribute__((ext_vector_type(4)));

// ---------------------------------------------------------------------------
// Kernel 0: w2[k] = w[k]^2  (one-time, 40 KB into d_ws)
// ---------------------------------------------------------------------------
__global__ void w2_kernel(const float* __restrict__ w, float* __restrict__ w2) {
    int i = blockIdx.x * 256 + threadIdx.x;
    if (i < NROW) { float v = w[i]; w2[i] = v * v; }
}

// ---------------------------------------------------------------------------
// Kernel 1: F[row] = sum_k g[row,k] * w2[k]
// 1250 blocks x 512 threads, one wave per row (10000 waves — R6 lesson:
// keep waves numerous, per-wave state small). No LDS, no barrier.
// w2 read through L1/L2; g streamed non-temporal (keeps L2/L1 clean).
// Uniform main loop: 2496 f32x4 = exactly 39 iters per lane, no predication;
// 4-element tail for lanes 0-3. unroll 8 -> 16 loads in flight per wave.
// ---------------------------------------------------------------------------
__global__ __launch_bounds__(512) void f_kernel(const float* __restrict__ g,
                                                const float* __restrict__ w2,
                                                float* __restrict__ Fout) {
    const int tid  = threadIdx.x;
    const int lane = tid & 63;
    const int row  = blockIdx.x * RPB + (tid >> 6);

    const f32x4* grow = (const f32x4*)(g + (size_t)row * NROW);
    const f32x4* wv4  = (const f32x4*)w2;
    f32x4 acc4 = {0.f, 0.f, 0.f, 0.f};

    int c = lane;
    #pragma unroll 8
    for (; c < 2496; c += 64)                      // 39 uniform iterations
        acc4 += __builtin_nontemporal_load(grow + c) * wv4[c];
    if (c < NROW / 4)                               // lanes 0..3 tail
        acc4 += __builtin_nontemporal_load(grow + c) * wv4[c];

    float acc = acc4.x + acc4.y + acc4.z + acc4.w;
    #pragma unroll
    for (int off = 32; off; off >>= 1) acc += __shfl_down(acc, off, 64);
    if (lane == 0) Fout[row] = acc;
}

// ---------------------------------------------------------------------------
// Kernel 2: Z[b,n] = sum_p sum_m softmax_m(-alpha[x_i[b,p]] * F[n,m]) * x[b,m,p]
// 512 blocks = (b, quarter-of-rows). 16 lanes per row n; lane q<12 computes
// the whole softmax for p=q (100 serial iters). 25 F-rows staged (10 KB,
// stride 101). Group-of-16 shfl_xor reduces.
// Softmax stabilized via per-row min of F (alpha > 0 => max(-a*F) = -a*minF).
// ---------------------------------------------------------------------------
__global__ __launch_bounds__(512) void z_kernel(const float* __restrict__ x,
                                                const float* __restrict__ alphas,
                                                const int*   __restrict__ xi,
                                                const float* __restrict__ F,
                                                float* __restrict__ Z) {
    const int bid = blockIdx.x;          // b*4 + nq
    const int b   = bid >> 2;
    const int nq  = bid & 3;
    const int n0  = nq * 25;
    __shared__ float Fs[25 * 101];
    __shared__ float xs[NN * PP];
    __shared__ float al[PP];
    const int tid = threadIdx.x;

    for (int j = tid; j < 25 * NN; j += 512) {
        int r = j / NN, m = j - r * NN;
        Fs[r * 101 + m] = F[(n0 + r) * NN + m];
    }
    for (int j = tid; j < NN * PP; j += 512)
        xs[j] = x[(size_t)b * (NN * PP) + j];
    if (tid < PP) al[tid] = alphas[xi[b * PP + tid]];
    __syncthreads();

    const int nl = tid >> 4;             // 0..31 (25 active)
    const int q  = tid & 15;
    if (nl < 25) {
        const float* Fr = &Fs[nl * 101];

        float rmin = 3.4e38f;
        for (int m = q; m < NN; m += 16) rmin = fminf(rmin, Fr[m]);
        rmin = fminf(rmin, __shfl_xor(rmin, 1, 64));
        rmin = fminf(rmin, __shfl_xor(rmin, 2, 64));
        rmin = fminf(rmin, __shfl_xor(rmin, 4, 64));
        rmin = fminf(rmin, __shfl_xor(rmin, 8, 64));

        float zacc = 0.f;
        if (q < PP) {
            const float a = al[q];
            float num = 0.f, den = 0.f;
            for (int m = 0; m < NN; m++) {
                float e = __expf(a * (rmin - Fr[m]));   // exponent <= 0
                num += e * xs[m * PP + q];
                den += e;
            }
            zacc = num / den;                           // den >= 1
        }
        zacc += __shfl_xor(zacc, 1, 64);
        zacc += __shfl_xor(zacc, 2, 64);
        zacc += __shfl_xor(zacc, 4, 64);
        zacc += __shfl_xor(zacc, 8, 64);
        if (q == 0) Z[b * NN + n0 + nl] = zacc;
    }
}

extern "C" void kernel_launch(void* const* d_in, const int* in_sizes, int n_in,
                              void* d_out, int out_size, void* d_ws, size_t ws_size,
                              hipStream_t stream) {
    const float* x      = (const float*)d_in[0];   // [128,100,12]
    const float* g      = (const float*)d_in[1];   // [10000,10000]
    const float* w      = (const float*)d_in[2];   // [10000,1]
    const float* alphas = (const float*)d_in[3];   // [4000,1]
    const int*   xi     = (const int*)d_in[4];     // [128,12]

    float* Z  = (float*)d_out;            // [128,100] -> 12800 floats
    float* F  = (float*)d_out + BB * NN;  // [10000]   -> next 10000 floats
    float* w2 = (float*)d_ws;             // 40 KB scratch

    w2_kernel<<<(NROW + 255) / 256, 256, 0, stream>>>(w, w2);
    f_kernel<<<NROW / RPB, 512, 0, stream>>>(g, w2, F);
    z_kernel<<<BB * 4, 512, 0, stream>>>(x, alphas, xi, F, Z);
}

// Round 8
// 73.648 us; speedup vs baseline: 2.0703x; 1.1170x over previous
//
#include <hip/hip_runtime.h>

// Problem constants (from reference setup_inputs)
#define NROW 10000   // N*N
#define NN   100     // N
#define PP   12      // p
#define BB   128     // batch
#define RPB  8       // rows per block in f_kernel

typedef float f32x4 __attribute__((ext_vector_type(4)));

// ---------------------------------------------------------------------------
// Kernel 1: F[row] = sum_k g[row,k] * w[k]^2
// 1250 blocks x 512 threads, one wave per row. Single-variable change vs R7:
// w^2 served from LDS (lgkm path) instead of L1 (vmem path). R7's hot loop
// ran TWO vmem streams (g + w2); w2's 40KB working set thrashed the 32KB L1
// for all 32 resident waves. Now the vmcnt/L1 path carries ONLY the nt
// g-stream; w^2 is squared once into LDS at block start (w read from L2,
// 50MB chip-wide ~ 1.5us). Also deletes the separate w2_kernel launch.
// ---------------------------------------------------------------------------
__global__ __launch_bounds__(512) void f_kernel(const float* __restrict__ g,
                                                const float* __restrict__ w,
                                                float* __restrict__ Fout) {
    __shared__ f32x4 ws4[NROW / 4];           // 40 KB of w^2
    const int tid  = threadIdx.x;
    const int lane = tid & 63;
    const int row  = blockIdx.x * RPB + (tid >> 6);

    const f32x4* wv4 = (const f32x4*)w;
    for (int c = tid; c < NROW / 4; c += 512) {
        f32x4 v = wv4[c];
        ws4[c] = v * v;
    }
    __syncthreads();

    const f32x4* grow = (const f32x4*)(g + (size_t)row * NROW);
    f32x4 acc4 = {0.f, 0.f, 0.f, 0.f};

    int c = lane;
    #pragma unroll 8
    for (; c < 2496; c += 64)                      // 39 uniform iterations
        acc4 += __builtin_nontemporal_load(grow + c) * ws4[c];
    if (c < NROW / 4)                               // lanes 0..3 tail
        acc4 += __builtin_nontemporal_load(grow + c) * ws4[c];

    float acc = acc4.x + acc4.y + acc4.z + acc4.w;
    #pragma unroll
    for (int off = 32; off; off >>= 1) acc += __shfl_down(acc, off, 64);
    if (lane == 0) Fout[row] = acc;
}

// ---------------------------------------------------------------------------
// Kernel 2: Z[b,n] = sum_p sum_m softmax_m(-alpha[x_i[b,p]] * F[n,m]) * x[b,m,p]
// 512 blocks = (b, quarter-of-rows). 16 lanes per row n; lane q<12 computes
// the whole softmax for p=q (100 serial iters). 25 F-rows staged (10 KB,
// stride 101). Group-of-16 shfl_xor reduces.
// Softmax stabilized via per-row min of F (alpha > 0 => max(-a*F) = -a*minF).
// ---------------------------------------------------------------------------
__global__ __launch_bounds__(512) void z_kernel(const float* __restrict__ x,
                                                const float* __restrict__ alphas,
                                                const int*   __restrict__ xi,
                                                const float* __restrict__ F,
                                                float* __restrict__ Z) {
    const int bid = blockIdx.x;          // b*4 + nq
    const int b   = bid >> 2;
    const int nq  = bid & 3;
    const int n0  = nq * 25;
    __shared__ float Fs[25 * 101];
    __shared__ float xs[NN * PP];
    __shared__ float al[PP];
    const int tid = threadIdx.x;

    for (int j = tid; j < 25 * NN; j += 512) {
        int r = j / NN, m = j - r * NN;
        Fs[r * 101 + m] = F[(n0 + r) * NN + m];
    }
    for (int j = tid; j < NN * PP; j += 512)
        xs[j] = x[(size_t)b * (NN * PP) + j];
    if (tid < PP) al[tid] = alphas[xi[b * PP + tid]];
    __syncthreads();

    const int nl = tid >> 4;             // 0..31 (25 active)
    const int q  = tid & 15;
    if (nl < 25) {
        const float* Fr = &Fs[nl * 101];

        float rmin = 3.4e38f;
        for (int m = q; m < NN; m += 16) rmin = fminf(rmin, Fr[m]);
        rmin = fminf(rmin, __shfl_xor(rmin, 1, 64));
        rmin = fminf(rmin, __shfl_xor(rmin, 2, 64));
        rmin = fminf(rmin, __shfl_xor(rmin, 4, 64));
        rmin = fminf(rmin, __shfl_xor(rmin, 8, 64));

        float zacc = 0.f;
        if (q < PP) {
            const float a = al[q];
            float num = 0.f, den = 0.f;
            for (int m = 0; m < NN; m++) {
                float e = __expf(a * (rmin - Fr[m]));   // exponent <= 0
                num += e * xs[m * PP + q];
                den += e;
            }
            zacc = num / den;                           // den >= 1
        }
        zacc += __shfl_xor(zacc, 1, 64);
        zacc += __shfl_xor(zacc, 2, 64);
        zacc += __shfl_xor(zacc, 4, 64);
        zacc += __shfl_xor(zacc, 8, 64);
        if (q == 0) Z[b * NN + n0 + nl] = zacc;
    }
}

extern "C" void kernel_launch(void* const* d_in, const int* in_sizes, int n_in,
                              void* d_out, int out_size, void* d_ws, size_t ws_size,
                              hipStream_t stream) {
    const float* x      = (const float*)d_in[0];   // [128,100,12]
    const float* g      = (const float*)d_in[1];   // [10000,10000]
    const float* w      = (const float*)d_in[2];   // [10000,1]
    const float* alphas = (const float*)d_in[3];   // [4000,1]
    const int*   xi     = (const int*)d_in[4];     // [128,12]

    float* Z = (float*)d_out;            // [128,100] -> 12800 floats
    float* F = (float*)d_out + BB * NN;  // [10000]   -> next 10000 floats

    f_kernel<<<NROW / RPB, 512, 0, stream>>>(g, w, F);
    z_kernel<<<BB * 4, 512, 0, stream>>>(x, alphas, xi, F, Z);
}

// Round 9
// 72.604 us; speedup vs baseline: 2.1000x; 1.0144x over previous
//
#include <hip/hip_runtime.h>

// Problem constants (from reference setup_inputs)
#define NROW 10000   // N*N
#define NN   100     // N
#define PP   12      // p
#define BB   128     // batch
#define RPB  8       // rows per block in f_kernel

typedef float f32x4 __attribute__((ext_vector_type(4)));

// ---------------------------------------------------------------------------
// Kernel 1: F[row] = sum_k g[row,k] * w[k]^2
// 1250 blocks x 512 threads, one wave per row. w^2 in LDS (lgkm path),
// g streamed non-temporal (nt is protective: keeps streaming g out of L2 so
// the per-block 40KB w prologue stays L2-hot — R4 showed -nt costs ~8us).
// Change vs R8: #pragma unroll 13 — 39 iters = 3x13 exact, removes the
// remainder loop and raises in-flight nt loads 8 -> 13 per wave.
// ---------------------------------------------------------------------------
__global__ __launch_bounds__(512) void f_kernel(const float* __restrict__ g,
                                                const float* __restrict__ w,
                                                float* __restrict__ Fout) {
    __shared__ f32x4 ws4[NROW / 4];           // 40 KB of w^2
    const int tid  = threadIdx.x;
    const int lane = tid & 63;
    const int row  = blockIdx.x * RPB + (tid >> 6);

    const f32x4* wv4 = (const f32x4*)w;
    for (int c = tid; c < NROW / 4; c += 512) {
        f32x4 v = wv4[c];
        ws4[c] = v * v;
    }
    __syncthreads();

    const f32x4* grow = (const f32x4*)(g + (size_t)row * NROW);
    f32x4 acc4 = {0.f, 0.f, 0.f, 0.f};

    int c = lane;
    #pragma unroll 13
    for (; c < 2496; c += 64)                      // 39 = 3x13 uniform iters
        acc4 += __builtin_nontemporal_load(grow + c) * ws4[c];
    if (c < NROW / 4)                               // lanes 0..3 tail
        acc4 += __builtin_nontemporal_load(grow + c) * ws4[c];

    float acc = acc4.x + acc4.y + acc4.z + acc4.w;
    #pragma unroll
    for (int off = 32; off; off >>= 1) acc += __shfl_down(acc, off, 64);
    if (lane == 0) Fout[row] = acc;
}

// ---------------------------------------------------------------------------
// Kernel 2: Z[b,n] = sum_p sum_m softmax_m(-alpha[x_i[b,p]] * F[n,m]) * x[b,m,p]
// 512 blocks = (b, quarter-of-rows). 16 lanes per row n; lane q<12 computes
// the whole softmax for p=q (100 serial iters). 25 F-rows staged (10 KB,
// stride 101). Group-of-16 shfl_xor reduces.
// Softmax stabilized via per-row min of F (alpha > 0 => max(-a*F) = -a*minF).
// ---------------------------------------------------------------------------
__global__ __launch_bounds__(512) void z_kernel(const float* __restrict__ x,
                                                const float* __restrict__ alphas,
                                                const int*   __restrict__ xi,
                                                const float* __restrict__ F,
                                                float* __restrict__ Z) {
    const int bid = blockIdx.x;          // b*4 + nq
    const int b   = bid >> 2;
    const int nq  = bid & 3;
    const int n0  = nq * 25;
    __shared__ float Fs[25 * 101];
    __shared__ float xs[NN * PP];
    __shared__ float al[PP];
    const int tid = threadIdx.x;

    for (int j = tid; j < 25 * NN; j += 512) {
        int r = j / NN, m = j - r * NN;
        Fs[r * 101 + m] = F[(n0 + r) * NN + m];
    }
    for (int j = tid; j < NN * PP; j += 512)
        xs[j] = x[(size_t)b * (NN * PP) + j];
    if (tid < PP) al[tid] = alphas[xi[b * PP + tid]];
    __syncthreads();

    const int nl = tid >> 4;             // 0..31 (25 active)
    const int q  = tid & 15;
    if (nl < 25) {
        const float* Fr = &Fs[nl * 101];

        float rmin = 3.4e38f;
        for (int m = q; m < NN; m += 16) rmin = fminf(rmin, Fr[m]);
        rmin = fminf(rmin, __shfl_xor(rmin, 1, 64));
        rmin = fminf(rmin, __shfl_xor(rmin, 2, 64));
        rmin = fminf(rmin, __shfl_xor(rmin, 4, 64));
        rmin = fminf(rmin, __shfl_xor(rmin, 8, 64));

        float zacc = 0.f;
        if (q < PP) {
            const float a = al[q];
            float num = 0.f, den = 0.f;
            for (int m = 0; m < NN; m++) {
                float e = __expf(a * (rmin - Fr[m]));   // exponent <= 0
                num += e * xs[m * PP + q];
                den += e;
            }
            zacc = num / den;                           // den >= 1
        }
        zacc += __shfl_xor(zacc, 1, 64);
        zacc += __shfl_xor(zacc, 2, 64);
        zacc += __shfl_xor(zacc, 4, 64);
        zacc += __shfl_xor(zacc, 8, 64);
        if (q == 0) Z[b * NN + n0 + nl] = zacc;
    }
}

extern "C" void kernel_launch(void* const* d_in, const int* in_sizes, int n_in,
                              void* d_out, int out_size, void* d_ws, size_t ws_size,
                              hipStream_t stream) {
    const float* x      = (const float*)d_in[0];   // [128,100,12]
    const float* g      = (const float*)d_in[1];   // [10000,10000]
    const float* w      = (const float*)d_in[2];   // [10000,1]
    const float* alphas = (const float*)d_in[3];   // [4000,1]
    const int*   xi     = (const int*)d_in[4];     // [128,12]

    float* Z = (float*)d_out;            // [128,100] -> 12800 floats
    float* F = (float*)d_out + BB * NN;  // [10000]   -> next 10000 floats

    f_kernel<<<NROW / RPB, 512, 0, stream>>>(g, w, F);
    z_kernel<<<BB * 4, 512, 0, stream>>>(x, alphas, xi, F, Z);
}